// Round 1
// baseline (1208.326 us; speedup 1.0000x reference)
//
#include <hip/hip_runtime.h>

#define N 8192
#define NCHUNK 64
#define CHUNK (N / NCHUNK)   // 128 rows per column-pass block

// ---------------------------------------------------------------------------
// Row pass: r[i] = LSE_j(A[i][j] - c[j]).  One block per row; each thread
// holds 32 elements (8 x float4) in registers; two-sweep LSE (max, then sum).
// ---------------------------------------------------------------------------
__global__ __launch_bounds__(256) void row_lse_kernel(const float* __restrict__ A,
                                                      const float* __restrict__ c,
                                                      float* __restrict__ r,
                                                      int use_c)
{
    const int row = blockIdx.x;
    const int t   = threadIdx.x;
    const float4* __restrict__ Ar = (const float4*)(A + (size_t)row * N);
    const float4* __restrict__ c4 = (const float4*)c;

    float4 v[8];
#pragma unroll
    for (int k = 0; k < 8; ++k) {
        const int idx = t + (k << 8);            // float4 index within row
        float4 a = Ar[idx];
        if (use_c) {
            float4 cc = c4[idx];
            a.x -= cc.x; a.y -= cc.y; a.z -= cc.z; a.w -= cc.w;
        }
        v[k] = a;
    }

    float m = -1e30f;
#pragma unroll
    for (int k = 0; k < 8; ++k)
        m = fmaxf(m, fmaxf(fmaxf(v[k].x, v[k].y), fmaxf(v[k].z, v[k].w)));
#pragma unroll
    for (int off = 32; off > 0; off >>= 1)
        m = fmaxf(m, __shfl_xor(m, off));

    __shared__ float smax[4];
    __shared__ float ssum[4];
    const int wave = t >> 6;
    if ((t & 63) == 0) smax[wave] = m;
    __syncthreads();
    m = fmaxf(fmaxf(smax[0], smax[1]), fmaxf(smax[2], smax[3]));

    float s = 0.f;
#pragma unroll
    for (int k = 0; k < 8; ++k) {
        s += __expf(v[k].x - m);
        s += __expf(v[k].y - m);
        s += __expf(v[k].z - m);
        s += __expf(v[k].w - m);
    }
#pragma unroll
    for (int off = 32; off > 0; off >>= 1)
        s += __shfl_xor(s, off);
    if ((t & 63) == 0) ssum[wave] = s;
    __syncthreads();
    if (t == 0)
        r[row] = m + __logf(ssum[0] + ssum[1] + ssum[2] + ssum[3]);
}

// ---------------------------------------------------------------------------
// Column pass (stage 1): per (column, row-chunk) online LSE of A[i][j]-r[i].
// Each thread owns 4 adjacent columns via float4 loads (fully coalesced).
// Writes partial (max, scaled-sum) to pm/ps.
// ---------------------------------------------------------------------------
__global__ __launch_bounds__(256) void col_lse_partial_kernel(const float* __restrict__ A,
                                                              const float* __restrict__ r,
                                                              float* __restrict__ pm,
                                                              float* __restrict__ ps)
{
    const int t     = threadIdx.x;
    const int col4  = blockIdx.x * 256 + t;      // float4 column index (0..2047)
    const int chunk = blockIdx.y;
    const int row0  = chunk * CHUNK;

    __shared__ float rl[CHUNK];
    for (int i = t; i < CHUNK; i += 256) rl[i] = r[row0 + i];
    __syncthreads();

    const float4* __restrict__ Ap = (const float4*)(A + (size_t)row0 * N) + col4;

    float4 m = make_float4(-1e30f, -1e30f, -1e30f, -1e30f);
    float4 s = make_float4(0.f, 0.f, 0.f, 0.f);
    for (int i = 0; i < CHUNK; ++i) {
        const float rr = rl[i];                  // LDS broadcast, conflict-free
        float4 a = Ap[(size_t)i * (N / 4)];
        const float v0 = a.x - rr, v1 = a.y - rr, v2 = a.z - rr, v3 = a.w - rr;
        float n;
        n = fmaxf(m.x, v0); s.x = s.x * __expf(m.x - n) + __expf(v0 - n); m.x = n;
        n = fmaxf(m.y, v1); s.y = s.y * __expf(m.y - n) + __expf(v1 - n); m.y = n;
        n = fmaxf(m.z, v2); s.z = s.z * __expf(m.z - n) + __expf(v2 - n); m.z = n;
        n = fmaxf(m.w, v3); s.w = s.w * __expf(m.w - n) + __expf(v3 - n); m.w = n;
    }

    float4* pm4 = (float4*)pm;                   // [NCHUNK][N/4] float4
    float4* ps4 = (float4*)ps;
    pm4[(size_t)chunk * (N / 4) + col4] = m;
    ps4[(size_t)chunk * (N / 4) + col4] = s;
}

// ---------------------------------------------------------------------------
// Column pass (stage 2): combine NCHUNK partial LSEs per column.
// ---------------------------------------------------------------------------
__global__ __launch_bounds__(256) void col_reduce_kernel(const float* __restrict__ pm,
                                                         const float* __restrict__ ps,
                                                         float* __restrict__ c)
{
    const int col = blockIdx.x * 256 + threadIdx.x;
    float M = -1e30f;
#pragma unroll
    for (int k = 0; k < NCHUNK; ++k)
        M = fmaxf(M, pm[(size_t)k * N + col]);
    float S = 0.f;
#pragma unroll
    for (int k = 0; k < NCHUNK; ++k)
        S += ps[(size_t)k * N + col] * __expf(pm[(size_t)k * N + col] - M);
    c[col] = M + __logf(S);
}

// ---------------------------------------------------------------------------
// Final: out[i][j] = exp(A[i][j] - r[i] - c[j])
// ---------------------------------------------------------------------------
__global__ __launch_bounds__(256) void finalize_kernel(const float* __restrict__ A,
                                                       const float* __restrict__ r,
                                                       const float* __restrict__ c,
                                                       float* __restrict__ out)
{
    const int row = blockIdx.x;
    const int t   = threadIdx.x;
    const float rr = r[row];
    const float4* __restrict__ Ar = (const float4*)(A + (size_t)row * N);
    const float4* __restrict__ c4 = (const float4*)c;
    float4* __restrict__ Or = (float4*)(out + (size_t)row * N);
#pragma unroll
    for (int k = 0; k < 8; ++k) {
        const int idx = t + (k << 8);
        float4 a  = Ar[idx];
        float4 cc = c4[idx];
        float4 o;
        o.x = __expf(a.x - rr - cc.x);
        o.y = __expf(a.y - rr - cc.y);
        o.z = __expf(a.z - rr - cc.z);
        o.w = __expf(a.w - rr - cc.w);
        Or[idx] = o;
    }
}

extern "C" void kernel_launch(void* const* d_in, const int* in_sizes, int n_in,
                              void* d_out, int out_size, void* d_ws, size_t ws_size,
                              hipStream_t stream)
{
    const float* A = (const float*)d_in[0];
    float* out = (float*)d_out;

    // r, c in workspace (64 KB total).
    float* r = (float*)d_ws;             // N floats
    float* c = r + N;                    // N floats

    // Column-pass partials live in d_out scratch space (4 MB); finalize_kernel
    // fully overwrites d_out afterwards, so this is safe and deterministic.
    float* pm = out;                     // NCHUNK*N floats
    float* ps = pm + (size_t)NCHUNK * N; // NCHUNK*N floats

    for (int it = 0; it < 10; ++it) {
        hipLaunchKernelGGL(row_lse_kernel, dim3(N), dim3(256), 0, stream,
                           A, c, r, it /* use_c: false on first iteration */);
        hipLaunchKernelGGL(col_lse_partial_kernel, dim3(N / 1024, NCHUNK), dim3(256), 0, stream,
                           A, r, pm, ps);
        hipLaunchKernelGGL(col_reduce_kernel, dim3(N / 256), dim3(256), 0, stream,
                           pm, ps, c);
    }
    hipLaunchKernelGGL(finalize_kernel, dim3(N), dim3(256), 0, stream, A, r, c, out);
}